// Round 6
// baseline (1001.944 us; speedup 1.0000x reference)
//
#include <hip/hip_runtime.h>
#include <math.h>

// ---------------------------------------------------------------------------
// EquiformerPointHead — round 6: double-buffered (2-phase) GEMM pipeline,
// leaner kNN pass-A (top-1/part + padded chunks).
// N=10000, C0=256, C1=64, DEPTH=4, HEADS=4, DH=32, H=128, K=16, R=16
// ---------------------------------------------------------------------------

#define NPTS 10000

using f16x8 = __attribute__((ext_vector_type(8))) _Float16;
using f32x4 = __attribute__((ext_vector_type(4))) float;

__device__ __forceinline__ float gelu_f(float x) {
    float u = 0.7978845608028654f * (x + 0.044715f * x * x * x);
    return 0.5f * x * (1.0f + tanhf(u));
}
__device__ __forceinline__ float sigmoid_f(float x) {
    return 1.0f / (1.0f + expf(-x));
}
// async global->LDS: 16B per lane; LDS dest = wave-uniform base + lane*16.
__device__ __forceinline__ void gload16(const _Float16* src, _Float16* dst_lds) {
    __builtin_amdgcn_global_load_lds(
        (const __attribute__((address_space(1))) unsigned int*)(const void*)src,
        (__attribute__((address_space(3))) unsigned int*)(void*)dst_lds,
        16, 0, 0);
}

// ---------------------------------------------------------------------------
// fp16 MFMA GEMM, double-buffered global_load_lds staging (2-phase pipeline:
// issue next tile's loads BEFORE computing current; __syncthreads vmcnt(0)
// drain then waits loads that had the whole MFMA phase to land).
// C[MxN] = epi(A[MxK] @ Bt[NxK]^T). BM=64, BN in {64,128}, BK=64, 4 waves.
// LDS linear [row][8 chunks of 16B]; source chunk pre-swizzled chunk=s^(row&7);
// reads use the same XOR (2-way bank = free). OOB reads stay inside d_ws and
// are discarded on the guarded write.
// ---------------------------------------------------------------------------
template<int ACT, bool ADD, bool BIAS, bool GATED, int OUT16, int BN>
__global__ __launch_bounds__(256)
void hgemm_k(const _Float16* __restrict__ A, int lda,
             const _Float16* __restrict__ Bt,
             const float* __restrict__ bias,
             const float* __restrict__ gate,
             float* __restrict__ C, _Float16* __restrict__ Ch, int ldc,
             int M, int N, int K)
{
    constexpr int NI = BN / 32;
    __shared__ _Float16 As[2][64 * 64];
    __shared__ _Float16 Bs[2][BN * 64];
    const int bm = blockIdx.y * 64;
    const int bn = blockIdx.x * BN;
    const int tid = threadIdx.x;
    const int lane = tid & 63;
    const int wid = tid >> 6;
    const int wr = wid >> 1, wc = wid & 1;
    const int l15 = lane & 15, lg = lane >> 4;

    auto stage = [&](int b, int kt) {
        #pragma unroll
        for (int i = 0; i < 2; ++i) {            // A: 8 segs of 1KB, 2/wave
            int seg = wid * 2 + i;
            int slot = seg * 64 + lane;
            int row = slot >> 3;
            int chunk = (slot & 7) ^ (row & 7);
            gload16(A + (size_t)(bm + row) * lda + kt + chunk * 8, As[b] + seg * 512);
        }
        #pragma unroll
        for (int i = 0; i < BN / 32; ++i) {      // B: BN/8 segs
            int seg = wid * (BN / 32) + i;
            int slot = seg * 64 + lane;
            int row = slot >> 3;
            int chunk = (slot & 7) ^ (row & 7);
            gload16(Bt + (size_t)(bn + row) * K + kt + chunk * 8, Bs[b] + seg * 512);
        }
    };

    f32x4 acc[2][NI];
    #pragma unroll
    for (int mi = 0; mi < 2; ++mi)
        #pragma unroll
        for (int ni = 0; ni < NI; ++ni)
            #pragma unroll
            for (int r = 0; r < 4; ++r) acc[mi][ni][r] = 0.f;

    const int nk = K >> 6;
    stage(0, 0);
    __syncthreads();
    for (int ik = 0; ik < nk; ++ik) {
        const int c = ik & 1;
        if (ik + 1 < nk) stage(c ^ 1, (ik + 1) << 6);
        f16x8 af[2][2], bf[NI][2];
        #pragma unroll
        for (int mi = 0; mi < 2; ++mi) {
            int row = wr * 32 + mi * 16 + l15;
            #pragma unroll
            for (int kk = 0; kk < 2; ++kk)
                af[mi][kk] = ((const f16x8*)As[c])[row * 8 + ((kk * 4 + lg) ^ (row & 7))];
        }
        #pragma unroll
        for (int ni = 0; ni < NI; ++ni) {
            int row = wc * (BN / 2) + ni * 16 + l15;
            #pragma unroll
            for (int kk = 0; kk < 2; ++kk)
                bf[ni][kk] = ((const f16x8*)Bs[c])[row * 8 + ((kk * 4 + lg) ^ (row & 7))];
        }
        #pragma unroll
        for (int kk = 0; kk < 2; ++kk)
            #pragma unroll
            for (int mi = 0; mi < 2; ++mi)
                #pragma unroll
                for (int ni = 0; ni < NI; ++ni)
                    acc[mi][ni] = __builtin_amdgcn_mfma_f32_16x16x32_f16(af[mi][kk], bf[ni][kk], acc[mi][ni], 0, 0, 0);
        __syncthreads();
    }

    #pragma unroll
    for (int mi = 0; mi < 2; ++mi) {
        #pragma unroll
        for (int ni = 0; ni < NI; ++ni) {
            int col = bn + wc * (BN / 2) + ni * 16 + l15;
            #pragma unroll
            for (int r = 0; r < 4; ++r) {
                int row = bm + wr * 32 + mi * 16 + lg * 4 + r;
                if (row < M && col < N) {
                    float v = acc[mi][ni][r];
                    if (BIAS) v += bias[col];
                    if (ACT == 1) v = gelu_f(v);
                    if (ACT == 2) v = sigmoid_f(v);
                    if (GATED) v *= gate[(size_t)(row / 3) * 64 + col];
                    size_t o = (size_t)row * ldc + col;
                    if (ADD) v += C[o];
                    if (OUT16 != 1) C[o] = v;
                    if (OUT16 >= 1) Ch[o] = (_Float16)v;
                }
            }
        }
    }
}

// ---------------------------------------------------------------------------
// LayerNorm-fused GEMM: A = f0 fp32 [M x 256]; block LN-normalizes its 64 rows
// once into a full-K LDS tile (f16, swizzled) while tile-0 B loads fly, then
// double-buffered K-loop over B. ACT 0: Ch = A_ln @ B. ACT 3: col<1024 ->
// gelu(.+bias)->Ch; col in [1024,1088) -> sigmoid -> gout[row*64+col-1024].
// ---------------------------------------------------------------------------
template<int ACT, bool BIAS, int BN>
__global__ __launch_bounds__(256)
void lngemm_k(const float* __restrict__ A,
              const _Float16* __restrict__ Bt,
              const float* __restrict__ bias,
              float* __restrict__ gout,
              _Float16* __restrict__ Ch, int ldc,
              int M, int N)
{
    constexpr int NI = BN / 32;
    __shared__ _Float16 As[64 * 256];          // 32 KB, staged once
    __shared__ _Float16 Bs[2][BN * 64];
    const int bm = blockIdx.y * 64;
    const int bn = blockIdx.x * BN;
    const int tid = threadIdx.x;
    const int lane = tid & 63;
    const int wid = tid >> 6;
    const int wr = wid >> 1, wc = wid & 1;
    const int l15 = lane & 15, lg = lane >> 4;

    auto stageB = [&](int b, int kt) {
        #pragma unroll
        for (int i = 0; i < BN / 32; ++i) {
            int seg = wid * (BN / 32) + i;
            int slot = seg * 64 + lane;
            int row = slot >> 3;
            int chunk = (slot & 7) ^ (row & 7);
            gload16(Bt + (size_t)(bn + row) * 256 + kt + chunk * 8, Bs[b] + seg * 512);
        }
    };

    stageB(0, 0);                               // tile-0 B loads overlap LN

    {   // ---- LN stage: 4 threads per row, 64 f32 each ----
        int r = tid >> 2, q4 = tid & 3;
        float4 v[16];
        if (bm + r < M) {
            const float4* src = (const float4*)(A + (size_t)(bm + r) * 256 + q4 * 64);
            #pragma unroll
            for (int i = 0; i < 16; ++i) v[i] = src[i];
        } else {
            #pragma unroll
            for (int i = 0; i < 16; ++i) v[i] = make_float4(0.f, 0.f, 0.f, 0.f);
        }
        float s1 = 0.f, s2 = 0.f;
        #pragma unroll
        for (int i = 0; i < 16; ++i) {
            s1 += v[i].x + v[i].y + v[i].z + v[i].w;
            s2 += v[i].x * v[i].x + v[i].y * v[i].y + v[i].z * v[i].z + v[i].w * v[i].w;
        }
        s1 += __shfl_xor(s1, 1); s1 += __shfl_xor(s1, 2);
        s2 += __shfl_xor(s2, 1); s2 += __shfl_xor(s2, 2);
        float mean = s1 * 0.00390625f;
        float var = s2 * 0.00390625f - mean * mean;
        float rs = rsqrtf(var + 1e-6f);
        #pragma unroll
        for (int j = 0; j < 8; ++j) {
            float4 a = v[2 * j], b = v[2 * j + 1];
            f16x8 o = {(_Float16)((a.x - mean) * rs), (_Float16)((a.y - mean) * rs),
                       (_Float16)((a.z - mean) * rs), (_Float16)((a.w - mean) * rs),
                       (_Float16)((b.x - mean) * rs), (_Float16)((b.y - mean) * rs),
                       (_Float16)((b.z - mean) * rs), (_Float16)((b.w - mean) * rs)};
            ((f16x8*)As)[r * 32 + q4 * 8 + (j ^ (r & 7))] = o;
        }
    }

    f32x4 acc[2][NI];
    #pragma unroll
    for (int mi = 0; mi < 2; ++mi)
        #pragma unroll
        for (int ni = 0; ni < NI; ++ni)
            #pragma unroll
            for (int r = 0; r < 4; ++r) acc[mi][ni][r] = 0.f;

    __syncthreads();                            // As written + tile-0 B landed
    for (int ik = 0; ik < 4; ++ik) {
        const int c = ik & 1;
        if (ik + 1 < 4) stageB(c ^ 1, (ik + 1) << 6);
        const int kt = ik << 6;
        f16x8 af[2][2], bf[NI][2];
        #pragma unroll
        for (int mi = 0; mi < 2; ++mi) {
            int row = wr * 32 + mi * 16 + l15;
            #pragma unroll
            for (int kk = 0; kk < 2; ++kk)
                af[mi][kk] = ((const f16x8*)As)[row * 32 + (kt >> 3) + ((kk * 4 + lg) ^ (row & 7))];
        }
        #pragma unroll
        for (int ni = 0; ni < NI; ++ni) {
            int row = wc * (BN / 2) + ni * 16 + l15;
            #pragma unroll
            for (int kk = 0; kk < 2; ++kk)
                bf[ni][kk] = ((const f16x8*)Bs[c])[row * 8 + ((kk * 4 + lg) ^ (row & 7))];
        }
        #pragma unroll
        for (int kk = 0; kk < 2; ++kk)
            #pragma unroll
            for (int mi = 0; mi < 2; ++mi)
                #pragma unroll
                for (int ni = 0; ni < NI; ++ni)
                    acc[mi][ni] = __builtin_amdgcn_mfma_f32_16x16x32_f16(af[mi][kk], bf[ni][kk], acc[mi][ni], 0, 0, 0);
        __syncthreads();
    }

    #pragma unroll
    for (int mi = 0; mi < 2; ++mi) {
        #pragma unroll
        for (int ni = 0; ni < NI; ++ni) {
            int col = bn + wc * (BN / 2) + ni * 16 + l15;
            #pragma unroll
            for (int r = 0; r < 4; ++r) {
                int row = bm + wr * 32 + mi * 16 + lg * 4 + r;
                if (row < M && col < N) {
                    float v = acc[mi][ni][r];
                    if (ACT == 3) {
                        if (col < 1024) {
                            if (BIAS) v += bias[col];
                            Ch[(size_t)row * ldc + col] = (_Float16)gelu_f(v);
                        } else {
                            gout[(size_t)row * 64 + (col - 1024)] = sigmoid_f(v);
                        }
                    } else {
                        Ch[(size_t)row * ldc + col] = (_Float16)v;
                    }
                }
            }
        }
    }
}

// ---------------------------------------------------------------------------
// Batched weight transpose-convert: src fp32 [K][N] -> dst f16 [N][K].
// ---------------------------------------------------------------------------
struct TXT { const float* src; _Float16* dst; int K, N, blk0; };
struct TXA { TXT t[46]; };

__global__ __launch_bounds__(256)
void tconv_k(TXA g)
{
    __shared__ float tile[32][33];
    int b = blockIdx.x;
    int d = 0;
    while (d < 45 && b >= g.t[d + 1].blk0) ++d;
    int local = b - g.t[d].blk0;
    const float* src = g.t[d].src;
    _Float16* dst = g.t[d].dst;
    int K = g.t[d].K, N = g.t[d].N;
    int ntj = N >> 5;
    int ti = local / ntj;
    int tj = local - ti * ntj;
    int tx = threadIdx.x & 31, ty = threadIdx.x >> 5;
    #pragma unroll
    for (int i = 0; i < 4; ++i)
        tile[ty + i * 8][tx] = src[(size_t)(ti * 32 + ty + i * 8) * N + tj * 32 + tx];
    __syncthreads();
    #pragma unroll
    for (int i = 0; i < 4; ++i)
        dst[(size_t)(tj * 32 + ty + i * 8) * K + ti * 32 + tx] = (_Float16)tile[tx][ty + i * 8];
}

// fp32 -> f16 elementwise (8 per thread)
__global__ __launch_bounds__(256)
void cvt_k(const float* __restrict__ src, _Float16* __restrict__ dst, int n8)
{
    int i = blockIdx.x * 256 + threadIdx.x;
    if (i >= n8) return;
    float4 a = ((const float4*)src)[2 * i];
    float4 b = ((const float4*)src)[2 * i + 1];
    f16x8 o = {(_Float16)a.x, (_Float16)a.y, (_Float16)a.z, (_Float16)a.w,
               (_Float16)b.x, (_Float16)b.y, (_Float16)b.z, (_Float16)b.w};
    ((f16x8*)dst)[i] = o;
}

// ---------------------------------------------------------------------------
// kNN — branchless 2-pass threshold, 8 queries x 64 parts per 512-thr block.
// Pass A: per-part MIN (single fminf). tau = 16th smallest of the 64 part-mins
// (16 distinct candidates => provable upper bound of true 16th distance).
// Chunks padded with 1e18 coords -> no per-candidate bounds checks.
// Pass B: collect d2 <= tau; parallel rank-based exact top-16 ((d2,idx) order).
// d2 in reference order, contract off (matches numpy top-k boundaries).
// ---------------------------------------------------------------------------
#define CH 1024
#define BUFCAP 192
__global__ __launch_bounds__(512)
void knn_k(const float* __restrict__ coors, int* __restrict__ idxp,
           float* __restrict__ rbfp, float* __restrict__ rup)
{
    #pragma clang fp contract(off)
    __shared__ float4 cf4[CH];
    __shared__ float pm[8][64];
    __shared__ float tauS[8];
    __shared__ int   cnt[8];
    __shared__ float bufD[8][BUFCAP];
    __shared__ int   bufJ[8][BUFCAP];
    __shared__ float selD[8][16];
    __shared__ int   selJ[8][16];

    const int t = threadIdx.x;
    const int qq = t & 7;
    const int part = t >> 3;              // 0..63
    const int n = blockIdx.x * 8 + qq;
    const float qx = coors[n * 3 + 0], qy = coors[n * 3 + 1], qz = coors[n * 3 + 2];

    // ---- pass A: per-part min ----
    float m0 = 3.4e38f;
    for (int cbase = 0; cbase < NPTS; cbase += CH) {
        int cn = min(CH, NPTS - cbase);
        __syncthreads();
        for (int i = t; i < cn; i += 512)
            cf4[i] = make_float4(coors[(cbase + i) * 3 + 0], coors[(cbase + i) * 3 + 1],
                                 coors[(cbase + i) * 3 + 2], 0.f);
        for (int i = cn + t; i < CH; i += 512)
            cf4[i] = make_float4(1e18f, 1e18f, 1e18f, 0.f);
        __syncthreads();
        for (int base = 0; base < cn; base += 256) {
            #pragma unroll
            for (int u = 0; u < 4; ++u) {
                float4 c = cf4[base + u * 64 + part];
                float dx = c.x - qx;
                float dy = c.y - qy;
                float dz = c.z - qz;
                float d2 = dx * dx + dy * dy;
                d2 = d2 + dz * dz;
                m0 = fminf(m0, d2);
            }
        }
    }
    pm[qq][part] = m0;
    if (t < 8) cnt[t] = 0;
    __syncthreads();

    // ---- tau = 16th smallest of 64 (rank-15 by (value,pos)), parallel ----
    {
        float v = pm[qq][part];
        int c = 0;
        for (int j = 0; j < 64; ++j) {
            float vj = pm[qq][j];
            c += (vj < v || (vj == v && j < part)) ? 1 : 0;
        }
        if (c == 15) tauS[qq] = v;
    }
    __syncthreads();
    const float tau = tauS[qq];

    // ---- pass B: collect qualifying candidates ----
    for (int cbase = 0; cbase < NPTS; cbase += CH) {
        int cn = min(CH, NPTS - cbase);
        __syncthreads();
        for (int i = t; i < cn; i += 512)
            cf4[i] = make_float4(coors[(cbase + i) * 3 + 0], coors[(cbase + i) * 3 + 1],
                                 coors[(cbase + i) * 3 + 2], 0.f);
        for (int i = cn + t; i < CH; i += 512)
            cf4[i] = make_float4(1e18f, 1e18f, 1e18f, 0.f);
        __syncthreads();
        for (int base = 0; base < cn; base += 256) {
            #pragma unroll
            for (int u = 0; u < 4; ++u) {
                int local = base + u * 64 + part;
                float4 c = cf4[local];
                float dx = c.x - qx;
                float dy = c.y - qy;
                float dz = c.z - qz;
                float d2 = dx * dx + dy * dy;
                d2 = d2 + dz * dz;
                if (d2 <= tau) {
                    int pos = atomicAdd(&cnt[qq], 1);
                    if (pos < BUFCAP) { bufD[qq][pos] = d2; bufJ[qq][pos] = cbase + local; }
                }
            }
        }
    }
    __syncthreads();

    // ---- exact top-16: parallel rank-based placement ----
    {
        int c = min(cnt[qq], BUFCAP);
        for (int i = part; i < c; i += 64) {
            float d = bufD[qq][i]; int j = bufJ[qq][i];
            int rank = 0;
            for (int k = 0; k < c; ++k) {
                float dk = bufD[qq][k]; int jk = bufJ[qq][k];
                rank += (dk < d || (dk == d && jk < j)) ? 1 : 0;
            }
            if (rank < 16) { selD[qq][rank] = d; selJ[qq][rank] = j; }
        }
    }
    __syncthreads();

    // ---- outputs: one (query, neighbor) pair per thread (first 128) ----
    if (t < 128) {
        int q = t >> 4, m = t & 15;
        int nn = blockIdx.x * 8 + q;
        int j = selJ[q][m];
        float d2 = selD[q][m];
        float dist = sqrtf(d2 + 1e-6f);
        float rx = coors[j * 3 + 0] - coors[nn * 3 + 0];
        float ry = coors[j * 3 + 1] - coors[nn * 3 + 1];
        float rz = coors[j * 3 + 2] - coors[nn * 3 + 2];
        idxp[nn * 16 + m] = j;
        rup[(nn * 16 + m) * 3 + 0] = rx / dist;
        rup[(nn * 16 + m) * 3 + 1] = ry / dist;
        rup[(nn * 16 + m) * 3 + 2] = rz / dist;
        #pragma unroll
        for (int r = 0; r < 16; ++r) {
            float cc = (4.0f / 15.0f) * r;
            float dd = dist - cc;
            rbfp[(size_t)nn * 256 + m * 16 + r] = expf(-dd * dd * 8.0f);
        }
    }
}

// ---------------------------------------------------------------------------
// Fused attention: 4 nodes per 512-thread block (shared We/Wer LDS).
// P per node: [q|k|v0|vr] f16 (512). V1 per node: 3x128 f16. O0/O1 f16 out.
// ---------------------------------------------------------------------------
__global__ __launch_bounds__(512)
void attn_k(const _Float16* __restrict__ P, const _Float16* __restrict__ V1,
            const float* __restrict__ rbf, const float* __restrict__ ru,
            const int* __restrict__ idx,
            const float* __restrict__ We, const float* __restrict__ Wer,
            _Float16* __restrict__ O0, _Float16* __restrict__ O1)
{
    const int t = threadIdx.x;
    const int sub = t >> 7;
    const int hd = t & 127;
    const int h = hd >> 5;
    const int n = blockIdx.x * 4 + sub;
    __shared__ float WeS[16][128], WerS[16][128];
    __shared__ float rbfS[4][16][16];
    __shared__ float ruS[4][16][4];
    __shared__ int   idxS[4][16];
    __shared__ float logitsS[4][4][16];
    __shared__ float attnS[4][4][16];

    #pragma unroll
    for (int i = 0; i < 4; ++i) {
        int ix = t + i * 512;
        WeS[ix >> 7][ix & 127]  = We[ix];
        WerS[ix >> 7][ix & 127] = Wer[ix];
    }
    ((float*)rbfS[sub])[hd]       = rbf[(size_t)n * 256 + hd];
    ((float*)rbfS[sub])[hd + 128] = rbf[(size_t)n * 256 + 128 + hd];
    if (hd < 16) idxS[sub][hd] = idx[n * 16 + hd];
    if (hd < 48) ruS[sub][hd / 3][hd % 3] = ru[n * 48 + hd];
    float q = (float)P[(size_t)n * 512 + hd];
    __syncthreads();

    #pragma unroll 4
    for (int k = 0; k < 16; ++k) {
        int j = idxS[sub][k];
        float kv = (float)P[(size_t)j * 512 + 128 + hd];
        float racc = 0.f;
        #pragma unroll
        for (int r = 0; r < 16; ++r) racc += rbfS[sub][k][r] * WeS[r][hd];
        kv += racc;
        float prod = q * kv;
        prod += __shfl_xor(prod, 1);
        prod += __shfl_xor(prod, 2);
        prod += __shfl_xor(prod, 4);
        prod += __shfl_xor(prod, 8);
        prod += __shfl_xor(prod, 16);
        if ((hd & 31) == 0) logitsS[sub][h][k] = prod * 0.17677669529663687f;
    }
    __syncthreads();

    {
        float mx = -1e30f;
        #pragma unroll
        for (int k = 0; k < 16; ++k) mx = fmaxf(mx, logitsS[sub][h][k]);
        float aw[16]; float s = 0.f;
        #pragma unroll
        for (int k = 0; k < 16; ++k) { aw[k] = expf(logitsS[sub][h][k] - mx); s += aw[k]; }
        float inv = 1.f / s;
        if ((hd & 31) == 0) {
            #pragma unroll
            for (int k = 0; k < 16; ++k) attnS[sub][h][k] = aw[k] * inv;
        }
    }
    __syncthreads();

    float o0 = 0.f, o1x = 0.f, o1y = 0.f, o1z = 0.f;
    #pragma unroll 4
    for (int k = 0; k < 16; ++k) {
        int j = idxS[sub][k];
        float a = attnS[sub][h][k];
        const _Float16* pj = P + (size_t)j * 512;
        float v0 = (float)pj[256 + hd];
        float ge = (float)pj[384 + hd];
        float racc = 0.f;
        #pragma unroll
        for (int r = 0; r < 16; ++r) racc += rbfS[sub][k][r] * WerS[r][hd];
        ge += racc;
        const _Float16* vj = V1 + (size_t)j * 384;
        o0  += a * v0;
        o1x += a * ((float)vj[hd]       + ge * ruS[sub][k][0]);
        o1y += a * ((float)vj[128 + hd] + ge * ruS[sub][k][1]);
        o1z += a * ((float)vj[256 + hd] + ge * ruS[sub][k][2]);
    }
    O0[(size_t)n * 128 + hd] = (_Float16)o0;
    _Float16* o1p = O1 + (size_t)n * 384;
    o1p[hd] = (_Float16)o1x; o1p[128 + hd] = (_Float16)o1y; o1p[256 + hd] = (_Float16)o1z;
}

// ---------------------------------------------------------------------------
__global__ __launch_bounds__(256)
void vecout_k(const float* __restrict__ f1, const float* __restrict__ wv,
              float* __restrict__ out2)
{
    int row = blockIdx.x * 256 + threadIdx.x;
    if (row >= NPTS * 3) return;
    const float4* fr = (const float4*)(f1 + (size_t)row * 64);
    const float4* w4 = (const float4*)wv;
    float s = 0.f;
    #pragma unroll
    for (int c = 0; c < 16; ++c) {
        float4 a = fr[c], b = w4[c];
        s += a.x * b.x + a.y * b.y + a.z * b.z + a.w * b.w;
    }
    out2[row] = s;
}

// ---------------------------------------------------------------------------
extern "C" void kernel_launch(void* const* d_in, const int* in_sizes, int n_in,
                              void* d_out, int out_size, void* d_ws, size_t ws_size,
                              hipStream_t stream)
{
    (void)in_sizes; (void)n_in; (void)out_size; (void)ws_size;
    const float* feats = (const float*)d_in[0];
    const float* coors = (const float*)d_in[1];
    const float* Wemb = (const float*)d_in[3];
    const float* Wq   = (const float*)d_in[4];
    const float* Wk   = (const float*)d_in[5];
    const float* Wv0  = (const float*)d_in[6];
    const float* Wvr  = (const float*)d_in[7];
    const float* We   = (const float*)d_in[8];
    const float* Wer  = (const float*)d_in[9];
    const float* Wv1  = (const float*)d_in[10];
    const float* Wo0  = (const float*)d_in[11];
    const float* Wo1  = (const float*)d_in[12];
    const float* Wf1  = (const float*)d_in[13];
    const float* bf1  = (const float*)d_in[14];
    const float* Wf2  = (const float*)d_in[15];
    const float* bf2  = (const float*)d_in[16];
    const float* Wg   = (const float*)d_in[17];
    const float* Wvff = (const float*)d_in[18];
    const float* Ws   = (const float*)d_in[19];
    const float* bs   = (const float*)d_in[20];
    const float* wv   = (const float*)d_in[21];
    float* out = (float*)d_out;

    char* ws = (char*)d_ws;
    size_t off = 0;
    auto carve = [&](size_t bytes) -> char* {
        char* p = ws + off;
        off += (bytes + 255) & ~(size_t)255;
        return p;
    };
    int*      idxp   = (int*)      carve((size_t)NPTS * 16 * 4);
    float*    rbfp   = (float*)    carve((size_t)NPTS * 256 * 4);
    float*    rup    = (float*)    carve((size_t)NPTS * 48 * 4);
    float*    f0     = (float*)    carve((size_t)NPTS * 256 * 4);
    float*    f1     = (float*)    carve((size_t)NPTS * 192 * 4);
    float*    gt     = (float*)    carve((size_t)NPTS * 64 * 4);
    _Float16* f0h    = (_Float16*) carve((size_t)NPTS * 256 * 2);
    _Float16* f1h    = (_Float16*) carve((size_t)NPTS * 192 * 2);
    _Float16* O1h    = (_Float16*) carve((size_t)NPTS * 384 * 2);
    _Float16* featsh = (_Float16*) carve((size_t)NPTS * 256 * 2);
    // Ph + V1h + O0h contiguous (10.24 + 7.68 + 2.56 MB = 20.48 MB);
    // Hbh (10000 x 1024 f16 = 20.48 MB) aliases them (all dead by FFN time).
    _Float16* Ph     = (_Float16*) carve((size_t)NPTS * 512 * 2);
    _Float16* V1h    = (_Float16*) carve((size_t)NPTS * 384 * 2);
    _Float16* O0h    = (_Float16*) carve((size_t)NPTS * 128 * 2);
    _Float16* Hbh    = Ph;
    _Float16* WembT  = (_Float16*) carve(65536 * 2);
    _Float16* WqkvrT = (_Float16*) carve(4 * 131072 * 2);
    _Float16* Wv1T   = (_Float16*) carve(4 * 8192 * 2);
    _Float16* Wo0T   = (_Float16*) carve(4 * 32768 * 2);
    _Float16* Wo1T   = (_Float16*) carve(4 * 8192 * 2);
    _Float16* WfgT   = (_Float16*) carve(4 * 278528 * 2);   // [Wf1(1024) ; Wg(64)] x 256
    _Float16* Wf2T   = (_Float16*) carve(4 * 262144 * 2);
    _Float16* WvffT  = (_Float16*) carve(4 * 4096 * 2);
    _Float16* WsT    = (_Float16*) carve(65536 * 2);

    // ---- weight transpose-convert (46 descriptors, one launch) ----
    TXA ta;
    int blk = 0, di = 0;
    auto addt = [&](const float* s, _Float16* d, int Ks, int Ns) {
        ta.t[di].src = s; ta.t[di].dst = d; ta.t[di].K = Ks; ta.t[di].N = Ns;
        ta.t[di].blk0 = blk; blk += (Ks / 32) * (Ns / 32); ++di;
    };
    addt(Wemb, WembT, 256, 256);
    for (int l = 0; l < 4; ++l) {
        addt(Wq  + l * 32768, WqkvrT + (size_t)l * 131072 +     0, 256, 128);
        addt(Wk  + l * 32768, WqkvrT + (size_t)l * 131072 + 32768, 256, 128);
        addt(Wv0 + l * 32768, WqkvrT + (size_t)l * 131072 + 65536, 256, 128);
        addt(Wvr + l * 32768, WqkvrT + (size_t)l * 131072 + 98304, 256, 128);
    }
    for (int l = 0; l < 4; ++l) addt(Wv1  + l * 8192,   Wv1T  + l * 8192,   64, 128);
    for (int l = 0; l < 4; ++l) addt(Wo0  + l * 32768,  Wo0T  + l * 32768,  128, 256);
    for (int l = 0; l < 4; ++l) addt(Wo1  + l * 8192,   Wo1T  + l * 8192,   128, 64);
    for (int l = 0; l < 4; ++l) {
        addt(Wf1 + l * 262144, WfgT + (size_t)l * 278528,          256, 1024);
        addt(Wg  + l * 16384,  WfgT + (size_t)l * 278528 + 262144, 256, 64);
    }
    for (int l = 0; l < 4; ++l) addt(Wf2  + l * 262144, Wf2T  + l * 262144, 1024, 256);
    for (int l = 0; l < 4; ++l) addt(Wvff + l * 4096,   WvffT + l * 4096,   64, 64);
    addt(Ws, WsT, 256, 256);
    tconv_k<<<blk, 256, 0, stream>>>(ta);

    cvt_k<<<1250, 256, 0, stream>>>(feats, featsh, NPTS * 256 / 8);
    knn_k<<<1250, 512, 0, stream>>>(coors, idxp, rbfp, rup);

    // f0 = feats @ Wemb
    hgemm_k<0,false,false,false,0,64><<<dim3(4,157),256,0,stream>>>(featsh,256,WembT,nullptr,nullptr,f0,nullptr,256,NPTS,256,256);
    hipMemsetAsync(f1, 0, (size_t)NPTS * 192 * 4, stream);
    hipMemsetAsync(f1h, 0, (size_t)NPTS * 192 * 2, stream);

    for (int l = 0; l < 4; ++l) {
        // Ph = f16( LN(f0) @ [Wq|Wk|Wv0|Wvr] )   (LN fused)
        lngemm_k<0,false,128><<<dim3(4,157),256,0,stream>>>(f0,WqkvrT+(size_t)l*131072,nullptr,nullptr,Ph,512,NPTS,512);
        // V1h = f16( f1 @ Wv1 )
        hgemm_k<0,false,false,false,1,64><<<dim3(2,469),256,0,stream>>>(f1h,64,Wv1T+l*8192,nullptr,nullptr,nullptr,V1h,128,NPTS*3,128,64);
        attn_k<<<2500,512,0,stream>>>(Ph, V1h, rbfp, rup, idxp, We + l*2048, Wer + l*2048, O0h, O1h);
        // f0 += O0 @ Wo0
        hgemm_k<0,true,false,false,0,64><<<dim3(4,157),256,0,stream>>>(O0h,128,Wo0T+l*32768,nullptr,nullptr,f0,nullptr,256,NPTS,256,128);
        // f1 += O1 @ Wo1 (+ f16 mirror)
        hgemm_k<0,true,false,false,2,64><<<dim3(1,469),256,0,stream>>>(O1h,128,Wo1T+l*8192,nullptr,nullptr,f1,f1h,64,NPTS*3,64,128);
        // Hb = gelu(LN(f0) @ Wf1 + bf1) f16; gate = sigmoid(LN(f0) @ Wg) — LN fused
        lngemm_k<3,true,128><<<dim3(9,157),256,0,stream>>>(f0,WfgT+(size_t)l*278528,bf1+l*1024,gt,Hbh,1024,NPTS,1088);
        // f0 += Hb @ Wf2 + bf2 (last layer also writes f0h)
        if (l < 3)
            hgemm_k<0,true,true,false,0,64><<<dim3(4,157),256,0,stream>>>(Hbh,1024,Wf2T+(size_t)l*262144,bf2+l*256,nullptr,f0,nullptr,256,NPTS,256,1024);
        else
            hgemm_k<0,true,true,false,2,64><<<dim3(4,157),256,0,stream>>>(Hbh,1024,Wf2T+(size_t)l*262144,bf2+l*256,nullptr,f0,f0h,256,NPTS,256,1024);
        // f1 += (f1 @ Wvff) * gate (+ f16 mirror)
        hgemm_k<0,true,false,true,2,64><<<dim3(1,469),256,0,stream>>>(f1h,64,WvffT+l*4096,nullptr,gt,f1,f1h,64,NPTS*3,64,64);
    }

    // pred_scalar = f0 @ Ws + bs
    hgemm_k<0,false,true,false,0,64><<<dim3(4,157),256,0,stream>>>(f0h,256,WsT,bs,nullptr,out,nullptr,256,NPTS,256,256);
    // pred_vector
    vecout_k<<<118,256,0,stream>>>(f1, wv, out + (size_t)NPTS * 256);
}

// Round 9
// 984.946 us; speedup vs baseline: 1.0173x; 1.0173x over previous
//
#include <hip/hip_runtime.h>
#include <math.h>
#include <string.h>

// ---------------------------------------------------------------------------
// EquiformerPointHead — round 9 (= round 7/8 resubmit): descriptor-batched
// GEMM (merged dispatches), single-buffered staging, 28 total dispatches.
// N=10000, C0=256, C1=64, DEPTH=4, HEADS=4, DH=32, H=128, K=16, R=16
// ---------------------------------------------------------------------------

#define NPTS 10000

using f16x8 = __attribute__((ext_vector_type(8))) _Float16;
using f32x4 = __attribute__((ext_vector_type(4))) float;

__device__ __forceinline__ float gelu_f(float x) {
    float u = 0.7978845608028654f * (x + 0.044715f * x * x * x);
    return 0.5f * x * (1.0f + tanhf(u));
}
__device__ __forceinline__ float sigmoid_f(float x) {
    return 1.0f / (1.0f + expf(-x));
}
__device__ __forceinline__ void gload16(const _Float16* src, _Float16* dst_lds) {
    __builtin_amdgcn_global_load_lds(
        (const __attribute__((address_space(1))) unsigned int*)(const void*)src,
        (__attribute__((address_space(3))) unsigned int*)(void*)dst_lds,
        16, 0, 0);
}

// ---------------------------------------------------------------------------
// Batched GEMM. Each dispatch carries up to 2 descriptors; blocks split by
// blk0. type 0: plain f16 GEMM, BM=64 BN=64 BK=64 (A f16 [M][lda], Bt f16
// [N][K]). type 1: LN-fused GEMM, BM=64 BN=128 (A = f0 fp32 [M][256],
// LN-normalized once into a 32KB LDS tile; Bt f16 [N][256]).
// Epilogue by mode bits. Dynamic LDS: 16KB (type0-only) or 48KB (with type1).
// LDS chunk-swizzle: lds slot s holds global chunk s^(row&7) (2-way = free).
// OOB A/B reads land in d_ws (discarded on guarded write).
// ---------------------------------------------------------------------------
#define MADD   1
#define MBIAS  2
#define MGATED 16
#define MO32   32
#define MO16   64
#define MSPLIT 128

struct GD {
    const _Float16* A; const float* Af; const _Float16* Bt;
    const float* bias; const float* gptr; float* gout;
    float* C; _Float16* Ch;
    int lda, ldc, M, N, K, mode, blk0, nbx, type;
};
struct GA { GD g[2]; int nd; };

__device__ __forceinline__ void epi(const GD& g, int row, int col, float v) {
    if (row >= g.M || col >= g.N) return;
    const int mode = g.mode;
    if (mode & MSPLIT) {
        if (col < 1024) {
            v += g.bias[col];
            g.Ch[(size_t)row * g.ldc + col] = (_Float16)gelu_f(v);
        } else {
            g.gout[(size_t)row * 64 + (col - 1024)] = sigmoid_f(v);
        }
        return;
    }
    if (mode & MBIAS)  v += g.bias[col];
    if (mode & MGATED) v *= g.gptr[(size_t)(row / 3) * 64 + col];
    size_t o = (size_t)row * g.ldc + col;
    if (mode & MADD) v += g.C[o];
    if (mode & MO32) g.C[o] = v;
    if (mode & MO16) g.Ch[o] = (_Float16)v;
}

__global__ __launch_bounds__(256)
void gemm_b(GA ga)
{
    extern __shared__ _Float16 lds[];
    int d = 0;
    if (ga.nd > 1 && (int)blockIdx.x >= ga.g[1].blk0) d = 1;
    const GD g = ga.g[d];
    const int local = blockIdx.x - g.blk0;
    const int by = local / g.nbx, bx = local - by * g.nbx;
    const int tid = threadIdx.x;
    const int lane = tid & 63;
    const int wid = tid >> 6;
    const int wr = wid >> 1, wc = wid & 1;
    const int l15 = lane & 15, lg = lane >> 4;
    const int bm = by * 64;

    if (g.type == 0) {
        _Float16* As = lds;            // 64 x 64
        _Float16* Bs = lds + 4096;     // 64 x 64
        const int bn = bx * 64;
        f32x4 acc[2][2];
        #pragma unroll
        for (int mi = 0; mi < 2; ++mi)
            #pragma unroll
            for (int ni = 0; ni < 2; ++ni)
                #pragma unroll
                for (int r = 0; r < 4; ++r) acc[mi][ni][r] = 0.f;

        const int nk = g.K >> 6;
        for (int ik = 0; ik < nk; ++ik) {
            const int kt = ik << 6;
            #pragma unroll
            for (int i = 0; i < 2; ++i) {
                int seg = wid * 2 + i;
                int slot = seg * 64 + lane;
                int row = slot >> 3;
                int chunk = (slot & 7) ^ (row & 7);
                gload16(g.A + (size_t)(bm + row) * g.lda + kt + chunk * 8, As + seg * 512);
            }
            #pragma unroll
            for (int i = 0; i < 2; ++i) {
                int seg = wid * 2 + i;
                int slot = seg * 64 + lane;
                int row = slot >> 3;
                int chunk = (slot & 7) ^ (row & 7);
                gload16(g.Bt + (size_t)(bn + row) * g.K + kt + chunk * 8, Bs + seg * 512);
            }
            __syncthreads();
            f16x8 af[2][2], bf[2][2];
            #pragma unroll
            for (int mi = 0; mi < 2; ++mi) {
                int row = wr * 32 + mi * 16 + l15;
                #pragma unroll
                for (int kk = 0; kk < 2; ++kk)
                    af[mi][kk] = ((const f16x8*)As)[row * 8 + ((kk * 4 + lg) ^ (row & 7))];
            }
            #pragma unroll
            for (int ni = 0; ni < 2; ++ni) {
                int row = wc * 32 + ni * 16 + l15;
                #pragma unroll
                for (int kk = 0; kk < 2; ++kk)
                    bf[ni][kk] = ((const f16x8*)Bs)[row * 8 + ((kk * 4 + lg) ^ (row & 7))];
            }
            #pragma unroll
            for (int kk = 0; kk < 2; ++kk)
                #pragma unroll
                for (int mi = 0; mi < 2; ++mi)
                    #pragma unroll
                    for (int ni = 0; ni < 2; ++ni)
                        acc[mi][ni] = __builtin_amdgcn_mfma_f32_16x16x32_f16(af[mi][kk], bf[ni][kk], acc[mi][ni], 0, 0, 0);
            __syncthreads();
        }
        #pragma unroll
        for (int mi = 0; mi < 2; ++mi)
            #pragma unroll
            for (int ni = 0; ni < 2; ++ni) {
                int col = bn + wc * 32 + ni * 16 + l15;
                #pragma unroll
                for (int r = 0; r < 4; ++r)
                    epi(g, bm + wr * 32 + mi * 16 + lg * 4 + r, col, acc[mi][ni][r]);
            }
    } else {
        _Float16* As = lds;            // 64 x 256 (32 KB)
        _Float16* Bs = lds + 16384;    // 128 x 64 (16 KB)
        const int bn = bx * 128;

        auto stageB = [&](int kt) {
            #pragma unroll
            for (int i = 0; i < 4; ++i) {
                int seg = wid * 4 + i;
                int slot = seg * 64 + lane;
                int row = slot >> 3;
                int chunk = (slot & 7) ^ (row & 7);
                gload16(g.Bt + (size_t)(bn + row) * 256 + kt + chunk * 8, Bs + seg * 512);
            }
        };
        stageB(0);                     // overlap tile-0 B with LN

        {   // LN: 4 threads per row, 64 f32 each
            int r = tid >> 2, q4 = tid & 3;
            float4 v[16];
            if (bm + r < g.M) {
                const float4* src = (const float4*)(g.Af + (size_t)(bm + r) * 256 + q4 * 64);
                #pragma unroll
                for (int i = 0; i < 16; ++i) v[i] = src[i];
            } else {
                #pragma unroll
                for (int i = 0; i < 16; ++i) v[i] = make_float4(0.f, 0.f, 0.f, 0.f);
            }
            float s1 = 0.f, s2 = 0.f;
            #pragma unroll
            for (int i = 0; i < 16; ++i) {
                s1 += v[i].x + v[i].y + v[i].z + v[i].w;
                s2 += v[i].x * v[i].x + v[i].y * v[i].y + v[i].z * v[i].z + v[i].w * v[i].w;
            }
            s1 += __shfl_xor(s1, 1); s1 += __shfl_xor(s1, 2);
            s2 += __shfl_xor(s2, 1); s2 += __shfl_xor(s2, 2);
            float mean = s1 * 0.00390625f;
            float var = s2 * 0.00390625f - mean * mean;
            float rs = rsqrtf(var + 1e-6f);
            #pragma unroll
            for (int j = 0; j < 8; ++j) {
                float4 a = v[2 * j], b = v[2 * j + 1];
                f16x8 o = {(_Float16)((a.x - mean) * rs), (_Float16)((a.y - mean) * rs),
                           (_Float16)((a.z - mean) * rs), (_Float16)((a.w - mean) * rs),
                           (_Float16)((b.x - mean) * rs), (_Float16)((b.y - mean) * rs),
                           (_Float16)((b.z - mean) * rs), (_Float16)((b.w - mean) * rs)};
                ((f16x8*)As)[r * 32 + q4 * 8 + (j ^ (r & 7))] = o;
            }
        }

        f32x4 acc[2][4];
        #pragma unroll
        for (int mi = 0; mi < 2; ++mi)
            #pragma unroll
            for (int ni = 0; ni < 4; ++ni)
                #pragma unroll
                for (int r = 0; r < 4; ++r) acc[mi][ni][r] = 0.f;

        __syncthreads();               // As written, B0 landed
        for (int ik = 0; ik < 4; ++ik) {
            f16x8 af[2][2], bf[4][2];
            #pragma unroll
            for (int mi = 0; mi < 2; ++mi) {
                int row = wr * 32 + mi * 16 + l15;
                #pragma unroll
                for (int kk = 0; kk < 2; ++kk)
                    af[mi][kk] = ((const f16x8*)As)[row * 32 + ik * 8 + ((kk * 4 + lg) ^ (row & 7))];
            }
            #pragma unroll
            for (int ni = 0; ni < 4; ++ni) {
                int row = wc * 64 + ni * 16 + l15;
                #pragma unroll
                for (int kk = 0; kk < 2; ++kk)
                    bf[ni][kk] = ((const f16x8*)Bs)[row * 8 + ((kk * 4 + lg) ^ (row & 7))];
            }
            #pragma unroll
            for (int kk = 0; kk < 2; ++kk)
                #pragma unroll
                for (int mi = 0; mi < 2; ++mi)
                    #pragma unroll
                    for (int ni = 0; ni < 4; ++ni)
                        acc[mi][ni] = __builtin_amdgcn_mfma_f32_16x16x32_f16(af[mi][kk], bf[ni][kk], acc[mi][ni], 0, 0, 0);
            if (ik < 3) {
                __syncthreads();       // all done reading Bs
                stageB((ik + 1) << 6);
                __syncthreads();       // next B landed
            }
        }
        #pragma unroll
        for (int mi = 0; mi < 2; ++mi)
            #pragma unroll
            for (int ni = 0; ni < 4; ++ni) {
                int col = bn + wc * 64 + ni * 16 + l15;
                #pragma unroll
                for (int r = 0; r < 4; ++r)
                    epi(g, bm + wr * 32 + mi * 16 + lg * 4 + r, col, acc[mi][ni][r]);
            }
    }
}

// ---------------------------------------------------------------------------
// Batched weight transpose-convert: src fp32 [K][N] -> dst f16 [N][K].
// ---------------------------------------------------------------------------
struct TXT { const float* src; _Float16* dst; int K, N, blk0; };
struct TXA { TXT t[46]; };

__global__ __launch_bounds__(256)
void tconv_k(TXA g)
{
    __shared__ float tile[32][33];
    int b = blockIdx.x;
    int d = 0;
    while (d < 45 && b >= g.t[d + 1].blk0) ++d;
    int local = b - g.t[d].blk0;
    const float* src = g.t[d].src;
    _Float16* dst = g.t[d].dst;
    int K = g.t[d].K, N = g.t[d].N;
    int ntj = N >> 5;
    int ti = local / ntj;
    int tj = local - ti * ntj;
    int tx = threadIdx.x & 31, ty = threadIdx.x >> 5;
    #pragma unroll
    for (int i = 0; i < 4; ++i)
        tile[ty + i * 8][tx] = src[(size_t)(ti * 32 + ty + i * 8) * N + tj * 32 + tx];
    __syncthreads();
    #pragma unroll
    for (int i = 0; i < 4; ++i)
        dst[(size_t)(tj * 32 + ty + i * 8) * K + ti * 32 + tx] = (_Float16)tile[tx][ty + i * 8];
}

// fp32 -> f16 elementwise (8 per thread)
__global__ __launch_bounds__(256)
void cvt_k(const float* __restrict__ src, _Float16* __restrict__ dst, int n8)
{
    int i = blockIdx.x * 256 + threadIdx.x;
    if (i >= n8) return;
    float4 a = ((const float4*)src)[2 * i];
    float4 b = ((const float4*)src)[2 * i + 1];
    f16x8 o = {(_Float16)a.x, (_Float16)a.y, (_Float16)a.z, (_Float16)a.w,
               (_Float16)b.x, (_Float16)b.y, (_Float16)b.z, (_Float16)b.w};
    ((f16x8*)dst)[i] = o;
}

// ---------------------------------------------------------------------------
// kNN — branchless 2-pass threshold, 8 queries x 64 parts per 512-thr block.
// (unchanged from round 6: 101 us)
// ---------------------------------------------------------------------------
#define CH 1024
#define BUFCAP 192
__global__ __launch_bounds__(512)
void knn_k(const float* __restrict__ coors, int* __restrict__ idxp,
           float* __restrict__ rbfp, float* __restrict__ rup)
{
    #pragma clang fp contract(off)
    __shared__ float4 cf4[CH];
    __shared__ float pm[8][64];
    __shared__ float tauS[8];
    __shared__ int   cnt[8];
    __shared__ float bufD[8][BUFCAP];
    __shared__ int   bufJ[8][BUFCAP];
    __shared__ float selD[8][16];
    __shared__ int   selJ[8][16];

    const int t = threadIdx.x;
    const int qq = t & 7;
    const int part = t >> 3;
    const int n = blockIdx.x * 8 + qq;
    const float qx = coors[n * 3 + 0], qy = coors[n * 3 + 1], qz = coors[n * 3 + 2];

    float m0 = 3.4e38f;
    for (int cbase = 0; cbase < NPTS; cbase += CH) {
        int cn = min(CH, NPTS - cbase);
        __syncthreads();
        for (int i = t; i < cn; i += 512)
            cf4[i] = make_float4(coors[(cbase + i) * 3 + 0], coors[(cbase + i) * 3 + 1],
                                 coors[(cbase + i) * 3 + 2], 0.f);
        for (int i = cn + t; i < CH; i += 512)
            cf4[i] = make_float4(1e18f, 1e18f, 1e18f, 0.f);
        __syncthreads();
        for (int base = 0; base < cn; base += 256) {
            #pragma unroll
            for (int u = 0; u < 4; ++u) {
                float4 c = cf4[base + u * 64 + part];
                float dx = c.x - qx;
                float dy = c.y - qy;
                float dz = c.z - qz;
                float d2 = dx * dx + dy * dy;
                d2 = d2 + dz * dz;
                m0 = fminf(m0, d2);
            }
        }
    }
    pm[qq][part] = m0;
    if (t < 8) cnt[t] = 0;
    __syncthreads();

    {
        float v = pm[qq][part];
        int c = 0;
        for (int j = 0; j < 64; ++j) {
            float vj = pm[qq][j];
            c += (vj < v || (vj == v && j < part)) ? 1 : 0;
        }
        if (c == 15) tauS[qq] = v;
    }
    __syncthreads();
    const float tau = tauS[qq];

    for (int cbase = 0; cbase < NPTS; cbase += CH) {
        int cn = min(CH, NPTS - cbase);
        __syncthreads();
        for (int i = t; i < cn; i += 512)
            cf4[i] = make_float4(coors[(cbase + i) * 3 + 0], coors[(cbase + i) * 3 + 1],
                                 coors[(cbase + i) * 3 + 2], 0.f);
        for (int i = cn + t; i < CH; i += 512)
            cf4[i] = make_float4(1e18f, 1e18f, 1e18f, 0.f);
        __syncthreads();
        for (int base = 0; base < cn; base += 256) {
            #pragma unroll
            for (int u = 0; u < 4; ++u) {
                int local = base + u * 64 + part;
                float4 c = cf4[local];
                float dx = c.x - qx;
                float dy = c.y - qy;
                float dz = c.z - qz;
                float d2 = dx * dx + dy * dy;
                d2 = d2 + dz * dz;
                if (d2 <= tau) {
                    int pos = atomicAdd(&cnt[qq], 1);
                    if (pos < BUFCAP) { bufD[qq][pos] = d2; bufJ[qq][pos] = cbase + local; }
                }
            }
        }
    }
    __syncthreads();

    {
        int c = min(cnt[qq], BUFCAP);
        for (int i = part; i < c; i += 64) {
            float d = bufD[qq][i]; int j = bufJ[qq][i];
            int rank = 0;
            for (int k = 0; k < c; ++k) {
                float dk = bufD[qq][k]; int jk = bufJ[qq][k];
                rank += (dk < d || (dk == d && jk < j)) ? 1 : 0;
            }
            if (rank < 16) { selD[qq][rank] = d; selJ[qq][rank] = j; }
        }
    }
    __syncthreads();

    if (t < 128) {
        int q = t >> 4, m = t & 15;
        int nn = blockIdx.x * 8 + q;
        int j = selJ[q][m];
        float d2 = selD[q][m];
        float dist = sqrtf(d2 + 1e-6f);
        float rx = coors[j * 3 + 0] - coors[nn * 3 + 0];
        float ry = coors[j * 3 + 1] - coors[nn * 3 + 1];
        float rz = coors[j * 3 + 2] - coors[nn * 3 + 2];
        idxp[nn * 16 + m] = j;
        rup[(nn * 16 + m) * 3 + 0] = rx / dist;
        rup[(nn * 16 + m) * 3 + 1] = ry / dist;
        rup[(nn * 16 + m) * 3 + 2] = rz / dist;
        #pragma unroll
        for (int r = 0; r < 16; ++r) {
            float cc = (4.0f / 15.0f) * r;
            float dd = dist - cc;
            rbfp[(size_t)nn * 256 + m * 16 + r] = expf(-dd * dd * 8.0f);
        }
    }
}

// ---------------------------------------------------------------------------
// Fused attention: 4 nodes per 512-thread block (shared We/Wer LDS).
// ---------------------------------------------------------------------------
__global__ __launch_bounds__(512)
void attn_k(const _Float16* __restrict__ P, const _Float16* __restrict__ V1,
            const float* __restrict__ rbf, const float* __restrict__ ru,
            const int* __restrict__ idx,
            const float* __restrict__ We, const float* __restrict__ Wer,
            _Float16* __restrict__ O0, _Float16* __restrict__ O1)
{
    const int t = threadIdx.x;
    const int sub = t >> 7;
    const int hd = t & 127;
    const int h = hd >> 5;
    const int n = blockIdx.x * 4 + sub;
    __shared__ float WeS[16][128], WerS[16][128];
    __shared__ float rbfS[4][16][16];
    __shared__ float ruS[4][16][4];
    __shared__ int   idxS[4][16];
    __shared__ float logitsS[4][4][16];
    __shared__ float attnS[4][4][16];

    #pragma unroll
    for (int i = 0; i < 4; ++i) {
        int ix = t + i * 512;
        WeS[ix >> 7][ix & 127]  = We[ix];
        WerS[ix >> 7][ix & 127] = Wer[ix];
    }
    ((float*)rbfS[sub])[hd]       = rbf[(size_t)n * 256 + hd];
    ((float*)rbfS[sub])[hd + 128] = rbf[(size_t)n * 256 + 128 + hd];
    if (hd < 16) idxS[sub][hd] = idx[n * 16 + hd];
    if (hd < 48) ruS[sub][hd / 3][hd % 3] = ru[n * 48 + hd];
    float q = (float)P[(size_t)n * 512 + hd];
    __syncthreads();

    #pragma unroll 4
    for (int k = 0; k < 16; ++k) {
        int j = idxS[sub][k];
        float kv = (float)P[(size_t)j * 512 + 128 + hd];
        float racc = 0.f;
        #pragma unroll
        for (int r = 0; r < 16; ++r) racc += rbfS[sub][k][r] * WeS[r][hd];
        kv += racc;
        float prod = q * kv;
        prod += __shfl_xor(prod, 1);
        prod += __shfl_xor(prod, 2);
        prod += __shfl_xor(prod, 4);
        prod += __shfl_xor(prod, 8);
        prod += __shfl_xor(prod, 16);
        if ((hd & 31) == 0) logitsS[sub][h][k] = prod * 0.17677669529663687f;
    }
    __syncthreads();

    {
        float mx = -1e30f;
        #pragma unroll
        for (int k = 0; k < 16; ++k) mx = fmaxf(mx, logitsS[sub][h][k]);
        float aw[16]; float s = 0.f;
        #pragma unroll
        for (int k = 0; k < 16; ++k) { aw[k] = expf(logitsS[sub][h][k] - mx); s += aw[k]; }
        float inv = 1.f / s;
        if ((hd & 31) == 0) {
            #pragma unroll
            for (int k = 0; k < 16; ++k) attnS[sub][h][k] = aw[k] * inv;
        }
    }
    __syncthreads();

    float o0 = 0.f, o1x = 0.f, o1y = 0.f, o1z = 0.f;
    #pragma unroll 4
    for (int k = 0; k < 16; ++k) {
        int j = idxS[sub][k];
        float a = attnS[sub][h][k];
        const _Float16* pj = P + (size_t)j * 512;
        float v0 = (float)pj[256 + hd];
        float ge = (float)pj[384 + hd];
        float racc = 0.f;
        #pragma unroll
        for (int r = 0; r < 16; ++r) racc += rbfS[sub][k][r] * WerS[r][hd];
        ge += racc;
        const _Float16* vj = V1 + (size_t)j * 384;
        o0  += a * v0;
        o1x += a * ((float)vj[hd]       + ge * ruS[sub][k][0]);
        o1y += a * ((float)vj[128 + hd] + ge * ruS[sub][k][1]);
        o1z += a * ((float)vj[256 + hd] + ge * ruS[sub][k][2]);
    }
    O0[(size_t)n * 128 + hd] = (_Float16)o0;
    _Float16* o1p = O1 + (size_t)n * 384;
    o1p[hd] = (_Float16)o1x; o1p[128 + hd] = (_Float16)o1y; o1p[256 + hd] = (_Float16)o1z;
}

// ---------------------------------------------------------------------------
__global__ __launch_bounds__(256)
void vecout_k(const float* __restrict__ f1, const float* __restrict__ wv,
              float* __restrict__ out2)
{
    int row = blockIdx.x * 256 + threadIdx.x;
    if (row >= NPTS * 3) return;
    const float4* fr = (const float4*)(f1 + (size_t)row * 64);
    const float4* w4 = (const float4*)wv;
    float s = 0.f;
    #pragma unroll
    for (int c = 0; c < 16; ++c) {
        float4 a = fr[c], b = w4[c];
        s += a.x * b.x + a.y * b.y + a.z * b.z + a.w * b.w;
    }
    out2[row] = s;
}

// ---------------------------------------------------------------------------
extern "C" void kernel_launch(void* const* d_in, const int* in_sizes, int n_in,
                              void* d_out, int out_size, void* d_ws, size_t ws_size,
                              hipStream_t stream)
{
    (void)in_sizes; (void)n_in; (void)out_size; (void)ws_size;
    const float* feats = (const float*)d_in[0];
    const float* coors = (const float*)d_in[1];
    const float* Wemb = (const float*)d_in[3];
    const float* Wq   = (const float*)d_in[4];
    const float* Wk   = (const float*)d_in[5];
    const float* Wv0  = (const float*)d_in[6];
    const float* Wvr  = (const float*)d_in[7];
    const float* We   = (const float*)d_in[8];
    const float* Wer  = (const float*)d_in[9];
    const float* Wv1  = (const float*)d_in[10];
    const float* Wo0  = (const float*)d_in[11];
    const float* Wo1  = (const float*)d_in[12];
    const float* Wf1  = (const float*)d_in[13];
    const float* bf1  = (const float*)d_in[14];
    const float* Wf2  = (const float*)d_in[15];
    const float* bf2  = (const float*)d_in[16];
    const float* Wg   = (const float*)d_in[17];
    const float* Wvff = (const float*)d_in[18];
    const float* Ws   = (const float*)d_in[19];
    const float* bs   = (const float*)d_in[20];
    const float* wv   = (const float*)d_in[21];
    float* out = (float*)d_out;

    char* ws = (char*)d_ws;
    size_t off = 0;
    auto carve = [&](size_t bytes) -> char* {
        char* p = ws + off;
        off += (bytes + 255) & ~(size_t)255;
        return p;
    };
    int*      idxp   = (int*)      carve((size_t)NPTS * 16 * 4);
    float*    rbfp   = (float*)    carve((size_t)NPTS * 256 * 4);
    float*    rup    = (float*)    carve((size_t)NPTS * 48 * 4);
    float*    f0     = (float*)    carve((size_t)NPTS * 256 * 4);
    float*    f1     = (float*)    carve((size_t)NPTS * 192 * 4);
    float*    gt     = (float*)    carve((size_t)NPTS * 64 * 4);
    _Float16* f0h    = (_Float16*) carve((size_t)NPTS * 256 * 2);
    _Float16* f1h    = (_Float16*) carve((size_t)NPTS * 192 * 2);
    _Float16* O1h    = (_Float16*) carve((size_t)NPTS * 384 * 2);
    _Float16* featsh = (_Float16*) carve((size_t)NPTS * 256 * 2);
    // Ph + V1h + O0h contiguous; Hbh (10000x1024 f16) aliases them.
    _Float16* Ph     = (_Float16*) carve((size_t)NPTS * 512 * 2);
    _Float16* V1h    = (_Float16*) carve((size_t)NPTS * 384 * 2);
    _Float16* O0h    = (_Float16*) carve((size_t)NPTS * 128 * 2);
    _Float16* Hbh    = Ph;
    _Float16* WembT  = (_Float16*) carve(65536 * 2);
    _Float16* WqkvrT = (_Float16*) carve(4 * 131072 * 2);
    _Float16* Wv1T   = (_Float16*) carve(4 * 8192 * 2);
    _Float16* Wo0T   = (_Float16*) carve(4 * 32768 * 2);
    _Float16* Wo1T   = (_Float16*) carve(4 * 8192 * 2);
    _Float16* WfgT   = (_Float16*) carve(4 * 278528 * 2);   // [Wf1(1024) ; Wg(64)] x 256
    _Float16* Wf2T   = (_Float16*) carve(4 * 262144 * 2);
    _Float16* WvffT  = (_Float16*) carve(4 * 4096 * 2);
    _Float16* WsT    = (_Float16*) carve(65536 * 2);

    // ---- weight transpose-convert (46 descriptors, one launch) ----
    TXA ta;
    int blk = 0, di = 0;
    auto addt = [&](const float* s, _Float16* d, int Ks, int Ns) {
        ta.t[di].src = s; ta.t[di].dst = d; ta.t[di].K = Ks; ta.t[di].N = Ns;
        ta.t[di].blk0 = blk; blk += (Ks / 32) * (Ns / 32); ++di;
    };
    addt(Wemb, WembT, 256, 256);
    for (int l = 0; l < 4; ++l) {
        addt(Wq  + l * 32768, WqkvrT + (size_t)l * 131072 +     0, 256, 128);
        addt(Wk  + l * 32768, WqkvrT + (size_t)l * 131072 + 32768, 256, 128);
        addt(Wv0 + l * 32768, WqkvrT + (size_t)l * 131072 + 65536, 256, 128);
        addt(Wvr + l * 32768, WqkvrT + (size_t)l * 131072 + 98304, 256, 128);
    }
    for (int l = 0; l < 4; ++l) addt(Wv1  + l * 8192,   Wv1T  + l * 8192,   64, 128);
    for (int l = 0; l < 4; ++l) addt(Wo0  + l * 32768,  Wo0T  + l * 32768,  128, 256);
    for (int l = 0; l < 4; ++l) addt(Wo1  + l * 8192,   Wo1T  + l * 8192,   128, 64);
    for (int l = 0; l < 4; ++l) {
        addt(Wf1 + l * 262144, WfgT + (size_t)l * 278528,          256, 1024);
        addt(Wg  + l * 16384,  WfgT + (size_t)l * 278528 + 262144, 256, 64);
    }
    for (int l = 0; l < 4; ++l) addt(Wf2  + l * 262144, Wf2T  + l * 262144, 1024, 256);
    for (int l = 0; l < 4; ++l) addt(Wvff + l * 4096,   WvffT + l * 4096,   64, 64);
    addt(Ws, WsT, 256, 256);
    tconv_k<<<blk, 256, 0, stream>>>(ta);

    cvt_k<<<1250, 256, 0, stream>>>(feats, featsh, NPTS * 256 / 8);
    knn_k<<<1250, 512, 0, stream>>>(coors, idxp, rbfp, rup);

    // f0 = feats @ Wemb
    {
        GA ga{}; ga.nd = 1;
        GD& g = ga.g[0];
        g.A = featsh; g.lda = 256; g.Bt = WembT; g.C = f0; g.ldc = 256;
        g.M = NPTS; g.N = 256; g.K = 256; g.mode = MO32; g.blk0 = 0; g.nbx = 4; g.type = 0;
        gemm_b<<<628, 256, 16384, stream>>>(ga);
    }
    (void)hipMemsetAsync(f1, 0, (size_t)NPTS * 192 * 4, stream);
    (void)hipMemsetAsync(f1h, 0, (size_t)NPTS * 192 * 2, stream);

    for (int l = 0; l < 4; ++l) {
        // merged1: Ph = f16(LN(f0) @ Wqkvr)  ||  V1h = f16(f1h @ Wv1)
        {
            GA ga{}; ga.nd = 2;
            GD& p = ga.g[0];
            p.Af = f0; p.Bt = WqkvrT + (size_t)l * 131072; p.Ch = Ph; p.ldc = 512;
            p.M = NPTS; p.N = 512; p.K = 256; p.mode = MO16; p.blk0 = 0; p.nbx = 4; p.type = 1;
            GD& v = ga.g[1];
            v.A = f1h; v.lda = 64; v.Bt = Wv1T + l * 8192; v.Ch = V1h; v.ldc = 128;
            v.M = NPTS * 3; v.N = 128; v.K = 64; v.mode = MO16; v.blk0 = 628; v.nbx = 2; v.type = 0;
            gemm_b<<<628 + 938, 256, 49152, stream>>>(ga);
        }
        attn_k<<<2500, 512, 0, stream>>>(Ph, V1h, rbfp, rup, idxp, We + l * 2048, Wer + l * 2048, O0h, O1h);
        // merged2: f0 += O0 @ Wo0  ||  f1 += O1 @ Wo1 (+ f16 mirror)
        {
            GA ga{}; ga.nd = 2;
            GD& a = ga.g[0];
            a.A = O0h; a.lda = 128; a.Bt = Wo0T + l * 32768; a.C = f0; a.ldc = 256;
            a.M = NPTS; a.N = 256; a.K = 128; a.mode = MADD | MO32; a.blk0 = 0; a.nbx = 4; a.type = 0;
            GD& b = ga.g[1];
            b.A = O1h; b.lda = 128; b.Bt = Wo1T + l * 8192; b.C = f1; b.Ch = f1h; b.ldc = 64;
            b.M = NPTS * 3; b.N = 64; b.K = 128; b.mode = MADD | MO32 | MO16; b.blk0 = 628; b.nbx = 1; b.type = 0;
            gemm_b<<<628 + 469, 256, 16384, stream>>>(ga);
        }
        // Wfg: Hb = gelu(LN(f0)@Wf1+bf1) f16; gate = sigmoid(LN(f0)@Wg)
        {
            GA ga{}; ga.nd = 1;
            GD& g = ga.g[0];
            g.Af = f0; g.Bt = WfgT + (size_t)l * 278528; g.bias = bf1 + l * 1024;
            g.Ch = Hbh; g.ldc = 1024; g.gout = gt;
            g.M = NPTS; g.N = 1088; g.K = 256; g.mode = MSPLIT | MBIAS; g.blk0 = 0; g.nbx = 9; g.type = 1;
            gemm_b<<<9 * 157, 256, 49152, stream>>>(ga);
        }
        // merged3: f0 += Hb @ Wf2 + bf2  ||  f1 += (f1h @ Wvff) * gate (+ mirror)
        {
            GA ga{}; ga.nd = 2;
            GD& a = ga.g[0];
            a.A = Hbh; a.lda = 1024; a.Bt = Wf2T + (size_t)l * 262144; a.bias = bf2 + l * 256;
            a.C = f0; a.ldc = 256;
            a.M = NPTS; a.N = 256; a.K = 1024;
            a.mode = MADD | MBIAS | MO32 | (l == 3 ? MO16 : 0);
            if (l == 3) a.Ch = f0h;
            a.blk0 = 0; a.nbx = 4; a.type = 0;
            GD& b = ga.g[1];
            b.A = f1h; b.lda = 64; b.Bt = WvffT + l * 4096; b.gptr = gt;
            b.C = f1; b.Ch = f1h; b.ldc = 64;
            b.M = NPTS * 3; b.N = 64; b.K = 64; b.mode = MADD | MGATED | MO32 | MO16;
            b.blk0 = 628; b.nbx = 1; b.type = 0;
            gemm_b<<<628 + 469, 256, 16384, stream>>>(ga);
        }
    }

    // pred_scalar = f0h @ Ws + bs
    {
        GA ga{}; ga.nd = 1;
        GD& g = ga.g[0];
        g.A = f0h; g.lda = 256; g.Bt = WsT; g.bias = bs; g.C = out; g.ldc = 256;
        g.M = NPTS; g.N = 256; g.K = 256; g.mode = MBIAS | MO32; g.blk0 = 0; g.nbx = 4; g.type = 0;
        gemm_b<<<628, 256, 16384, stream>>>(ga);
    }
    // pred_vector
    vecout_k<<<118, 256, 0, stream>>>(f1, wv, out + (size_t)NPTS * 256);
}

// Round 11
// 894.221 us; speedup vs baseline: 1.1205x; 1.1015x over previous
//
#include <hip/hip_runtime.h>
#include <math.h>

// ---------------------------------------------------------------------------
// EquiformerPointHead — round 11 (= round 10 resubmit): per-phase tagged
// GEMMs, LN separated (all GEMMs uniform type-0 64x64), DBUF prefetch on the
// K=1024 FFN2 GEMM.
// N=10000, C0=256, C1=64, DEPTH=4, HEADS=4, DH=32, H=128, K=16, R=16
// ---------------------------------------------------------------------------

#define NPTS 10000

using f16x8 = __attribute__((ext_vector_type(8))) _Float16;
using f16x4 = __attribute__((ext_vector_type(4))) _Float16;
using f32x4 = __attribute__((ext_vector_type(4))) float;

__device__ __forceinline__ float gelu_f(float x) {
    float u = 0.7978845608028654f * (x + 0.044715f * x * x * x);
    return 0.5f * x * (1.0f + tanhf(u));
}
__device__ __forceinline__ float sigmoid_f(float x) {
    return 1.0f / (1.0f + expf(-x));
}
__device__ __forceinline__ void gload16(const _Float16* src, _Float16* dst_lds) {
    __builtin_amdgcn_global_load_lds(
        (const __attribute__((address_space(1))) unsigned int*)(const void*)src,
        (__attribute__((address_space(3))) unsigned int*)(void*)dst_lds,
        16, 0, 0);
}

// ---------------------------------------------------------------------------
// Batched type-0 GEMM: BM=64, BN=64, BK=64, 256 thr = 4 waves (2x2).
// A f16 [M][lda], Bt f16 [N][K]. Up to 2 descriptors per dispatch (blk0 split).
// TAG distinguishes call-sites in rocprof. DBUF: double-buffered K pipeline
// (prefetch t+1 issued before MFMA(t); barrier drain overlaps MFMA).
// LDS chunk-swizzle: slot s holds global chunk s^(row&7) (2-way read = free).
// OOB reads land inside d_ws; discarded by guarded epilogue.
// ---------------------------------------------------------------------------
#define MADD   1
#define MBIAS  2
#define MGATED 16
#define MO32   32
#define MO16   64
#define MSPLIT 128

struct GD {
    const _Float16* A; const _Float16* Bt;
    const float* bias; const float* gptr; float* gout;
    float* C; _Float16* Ch;
    int lda, ldc, M, N, K, mode, blk0, nbx;
};
struct GA { GD g[2]; int nd; };

__device__ __forceinline__ void epi(const GD& g, int row, int col, float v) {
    if (row >= g.M || col >= g.N) return;
    const int mode = g.mode;
    if (mode & MSPLIT) {
        if (col < 1024) {
            v += g.bias[col];
            g.Ch[(size_t)row * g.ldc + col] = (_Float16)gelu_f(v);
        } else {
            g.gout[(size_t)row * 64 + (col - 1024)] = sigmoid_f(v);
        }
        return;
    }
    if (mode & MBIAS)  v += g.bias[col];
    if (mode & MGATED) v *= g.gptr[(size_t)(row / 3) * 64 + col];
    size_t o = (size_t)row * g.ldc + col;
    if (mode & MADD) v += g.C[o];
    if (mode & MO32) g.C[o] = v;
    if (mode & MO16) g.Ch[o] = (_Float16)v;
}

template<int TAG, bool DBUF>
__global__ __launch_bounds__(256)
void gemm_b(GA ga)
{
    __shared__ _Float16 As[(DBUF ? 2 : 1) * 4096];
    __shared__ _Float16 Bs[(DBUF ? 2 : 1) * 4096];
    int d = 0;
    if (ga.nd > 1 && (int)blockIdx.x >= ga.g[1].blk0) d = 1;
    const GD g = ga.g[d];
    const int local = blockIdx.x - g.blk0;
    const int by = local / g.nbx, bx = local - by * g.nbx;
    const int tid = threadIdx.x;
    const int lane = tid & 63;
    const int wid = tid >> 6;
    const int wr = wid >> 1, wc = wid & 1;
    const int l15 = lane & 15, lg = lane >> 4;
    const int bm = by * 64;
    const int bn = bx * 64;

    auto stage = [&](int b, int kt) {
        #pragma unroll
        for (int i = 0; i < 2; ++i) {
            int seg = wid * 2 + i;
            int slot = seg * 64 + lane;
            int row = slot >> 3;
            int chunk = (slot & 7) ^ (row & 7);
            gload16(g.A + (size_t)(bm + row) * g.lda + kt + chunk * 8, As + b * 4096 + seg * 512);
        }
        #pragma unroll
        for (int i = 0; i < 2; ++i) {
            int seg = wid * 2 + i;
            int slot = seg * 64 + lane;
            int row = slot >> 3;
            int chunk = (slot & 7) ^ (row & 7);
            gload16(g.Bt + (size_t)(bn + row) * g.K + kt + chunk * 8, Bs + b * 4096 + seg * 512);
        }
    };

    f32x4 acc[2][2];
    #pragma unroll
    for (int mi = 0; mi < 2; ++mi)
        #pragma unroll
        for (int ni = 0; ni < 2; ++ni)
            #pragma unroll
            for (int r = 0; r < 4; ++r) acc[mi][ni][r] = 0.f;

    const int nk = g.K >> 6;
    if (DBUF) stage(0, 0);
    if (DBUF) __syncthreads();
    for (int ik = 0; ik < nk; ++ik) {
        const int c = DBUF ? (ik & 1) : 0;
        if (DBUF) {
            if (ik + 1 < nk) stage(c ^ 1, (ik + 1) << 6);
        } else {
            stage(0, ik << 6);
            __syncthreads();
        }
        f16x8 af[2][2], bf[2][2];
        #pragma unroll
        for (int mi = 0; mi < 2; ++mi) {
            int row = wr * 32 + mi * 16 + l15;
            #pragma unroll
            for (int kk = 0; kk < 2; ++kk)
                af[mi][kk] = ((const f16x8*)(As + c * 4096))[row * 8 + ((kk * 4 + lg) ^ (row & 7))];
        }
        #pragma unroll
        for (int ni = 0; ni < 2; ++ni) {
            int row = wc * 32 + ni * 16 + l15;
            #pragma unroll
            for (int kk = 0; kk < 2; ++kk)
                bf[ni][kk] = ((const f16x8*)(Bs + c * 4096))[row * 8 + ((kk * 4 + lg) ^ (row & 7))];
        }
        #pragma unroll
        for (int kk = 0; kk < 2; ++kk)
            #pragma unroll
            for (int mi = 0; mi < 2; ++mi)
                #pragma unroll
                for (int ni = 0; ni < 2; ++ni)
                    acc[mi][ni] = __builtin_amdgcn_mfma_f32_16x16x32_f16(af[mi][kk], bf[ni][kk], acc[mi][ni], 0, 0, 0);
        __syncthreads();
    }
    #pragma unroll
    for (int mi = 0; mi < 2; ++mi)
        #pragma unroll
        for (int ni = 0; ni < 2; ++ni) {
            int col = bn + wc * 32 + ni * 16 + l15;
            #pragma unroll
            for (int r = 0; r < 4; ++r)
                epi(g, bm + wr * 32 + mi * 16 + lg * 4 + r, col, acc[mi][ni][r]);
        }
}

// ---------------------------------------------------------------------------
// LayerNorm over rows of 256, f16 output. One wave per row, 4 rows/block.
// ---------------------------------------------------------------------------
__global__ __launch_bounds__(256)
void ln_k(const float* __restrict__ x, _Float16* __restrict__ y, int M)
{
    int lane = threadIdx.x & 63;
    int row = blockIdx.x * 4 + (threadIdx.x >> 6);
    if (row >= M) return;
    float4 v = ((const float4*)(x + (size_t)row * 256))[lane];
    float s = v.x + v.y + v.z + v.w;
    #pragma unroll
    for (int m = 32; m >= 1; m >>= 1) s += __shfl_xor(s, m);
    float mean = s * 0.00390625f;
    float dx = v.x - mean, dy = v.y - mean, dz = v.z - mean, dw = v.w - mean;
    float vs = dx * dx + dy * dy + dz * dz + dw * dw;
    #pragma unroll
    for (int m = 32; m >= 1; m >>= 1) vs += __shfl_xor(vs, m);
    float rs = rsqrtf(vs * 0.00390625f + 1e-6f);
    f16x4 o = {(_Float16)(dx * rs), (_Float16)(dy * rs), (_Float16)(dz * rs), (_Float16)(dw * rs)};
    ((f16x4*)(y + (size_t)row * 256))[lane] = o;
}

// ---------------------------------------------------------------------------
// Batched weight transpose-convert: src fp32 [K][N] -> dst f16 [N][K].
// ---------------------------------------------------------------------------
struct TXT { const float* src; _Float16* dst; int K, N, blk0; };
struct TXA { TXT t[46]; };

__global__ __launch_bounds__(256)
void tconv_k(TXA g)
{
    __shared__ float tile[32][33];
    int b = blockIdx.x;
    int d = 0;
    while (d < 45 && b >= g.t[d + 1].blk0) ++d;
    int local = b - g.t[d].blk0;
    const float* src = g.t[d].src;
    _Float16* dst = g.t[d].dst;
    int K = g.t[d].K, N = g.t[d].N;
    int ntj = N >> 5;
    int ti = local / ntj;
    int tj = local - ti * ntj;
    int tx = threadIdx.x & 31, ty = threadIdx.x >> 5;
    #pragma unroll
    for (int i = 0; i < 4; ++i)
        tile[ty + i * 8][tx] = src[(size_t)(ti * 32 + ty + i * 8) * N + tj * 32 + tx];
    __syncthreads();
    #pragma unroll
    for (int i = 0; i < 4; ++i)
        dst[(size_t)(tj * 32 + ty + i * 8) * K + ti * 32 + tx] = (_Float16)tile[tx][ty + i * 8];
}

// fp32 -> f16 elementwise (8 per thread)
__global__ __launch_bounds__(256)
void cvt_k(const float* __restrict__ src, _Float16* __restrict__ dst, int n8)
{
    int i = blockIdx.x * 256 + threadIdx.x;
    if (i >= n8) return;
    float4 a = ((const float4*)src)[2 * i];
    float4 b = ((const float4*)src)[2 * i + 1];
    f16x8 o = {(_Float16)a.x, (_Float16)a.y, (_Float16)a.z, (_Float16)a.w,
               (_Float16)b.x, (_Float16)b.y, (_Float16)b.z, (_Float16)b.w};
    ((f16x8*)dst)[i] = o;
}

// ---------------------------------------------------------------------------
// kNN — branchless 2-pass threshold, 8 queries x 64 parts per 512-thr block.
// (unchanged from round 6: ~100 us)
// ---------------------------------------------------------------------------
#define CH 1024
#define BUFCAP 192
__global__ __launch_bounds__(512)
void knn_k(const float* __restrict__ coors, int* __restrict__ idxp,
           float* __restrict__ rbfp, float* __restrict__ rup)
{
    #pragma clang fp contract(off)
    __shared__ float4 cf4[CH];
    __shared__ float pm[8][64];
    __shared__ float tauS[8];
    __shared__ int   cnt[8];
    __shared__ float bufD[8][BUFCAP];
    __shared__ int   bufJ[8][BUFCAP];
    __shared__ float selD[8][16];
    __shared__ int   selJ[8][16];

    const int t = threadIdx.x;
    const int qq = t & 7;
    const int part = t >> 3;
    const int n = blockIdx.x * 8 + qq;
    const float qx = coors[n * 3 + 0], qy = coors[n * 3 + 1], qz = coors[n * 3 + 2];

    float m0 = 3.4e38f;
    for (int cbase = 0; cbase < NPTS; cbase += CH) {
        int cn = min(CH, NPTS - cbase);
        __syncthreads();
        for (int i = t; i < cn; i += 512)
            cf4[i] = make_float4(coors[(cbase + i) * 3 + 0], coors[(cbase + i) * 3 + 1],
                                 coors[(cbase + i) * 3 + 2], 0.f);
        for (int i = cn + t; i < CH; i += 512)
            cf4[i] = make_float4(1e18f, 1e18f, 1e18f, 0.f);
        __syncthreads();
        for (int base = 0; base < cn; base += 256) {
            #pragma unroll
            for (int u = 0; u < 4; ++u) {
                float4 c = cf4[base + u * 64 + part];
                float dx = c.x - qx;
                float dy = c.y - qy;
                float dz = c.z - qz;
                float d2 = dx * dx + dy * dy;
                d2 = d2 + dz * dz;
                m0 = fminf(m0, d2);
            }
        }
    }
    pm[qq][part] = m0;
    if (t < 8) cnt[t] = 0;
    __syncthreads();

    {
        float v = pm[qq][part];
        int c = 0;
        for (int j = 0; j < 64; ++j) {
            float vj = pm[qq][j];
            c += (vj < v || (vj == v && j < part)) ? 1 : 0;
        }
        if (c == 15) tauS[qq] = v;
    }
    __syncthreads();
    const float tau = tauS[qq];

    for (int cbase = 0; cbase < NPTS; cbase += CH) {
        int cn = min(CH, NPTS - cbase);
        __syncthreads();
        for (int i = t; i < cn; i += 512)
            cf4[i] = make_float4(coors[(cbase + i) * 3 + 0], coors[(cbase + i) * 3 + 1],
                                 coors[(cbase + i) * 3 + 2], 0.f);
        for (int i = cn + t; i < CH; i += 512)
            cf4[i] = make_float4(1e18f, 1e18f, 1e18f, 0.f);
        __syncthreads();
        for (int base = 0; base < cn; base += 256) {
            #pragma unroll
            for (int u = 0; u < 4; ++u) {
                int local = base + u * 64 + part;
                float4 c = cf4[local];
                float dx = c.x - qx;
                float dy = c.y - qy;
                float dz = c.z - qz;
                float d2 = dx * dx + dy * dy;
                d2 = d2 + dz * dz;
                if (d2 <= tau) {
                    int pos = atomicAdd(&cnt[qq], 1);
                    if (pos < BUFCAP) { bufD[qq][pos] = d2; bufJ[qq][pos] = cbase + local; }
                }
            }
        }
    }
    __syncthreads();

    {
        int c = min(cnt[qq], BUFCAP);
        for (int i = part; i < c; i += 64) {
            float d = bufD[qq][i]; int j = bufJ[qq][i];
            int rank = 0;
            for (int k = 0; k < c; ++k) {
                float dk = bufD[qq][k]; int jk = bufJ[qq][k];
                rank += (dk < d || (dk == d && jk < j)) ? 1 : 0;
            }
            if (rank < 16) { selD[qq][rank] = d; selJ[qq][rank] = j; }
        }
    }
    __syncthreads();

    if (t < 128) {
        int q = t >> 4, m = t & 15;
        int nn = blockIdx.x * 8 + q;
        int j = selJ[q][m];
        float d2 = selD[q][m];
        float dist = sqrtf(d2 + 1e-6f);
        float rx = coors[j * 3 + 0] - coors[nn * 3 + 0];
        float ry = coors[j * 3 + 1] - coors[nn * 3 + 1];
        float rz = coors[j * 3 + 2] - coors[nn * 3 + 2];
        idxp[nn * 16 + m] = j;
        rup[(nn * 16 + m) * 3 + 0] = rx / dist;
        rup[(nn * 16 + m) * 3 + 1] = ry / dist;
        rup[(nn * 16 + m) * 3 + 2] = rz / dist;
        #pragma unroll
        for (int r = 0; r < 16; ++r) {
            float cc = (4.0f / 15.0f) * r;
            float dd = dist - cc;
            rbfp[(size_t)nn * 256 + m * 16 + r] = expf(-dd * dd * 8.0f);
        }
    }
}

// ---------------------------------------------------------------------------
// Fused attention: 4 nodes per 512-thread block (shared We/Wer LDS).
// ---------------------------------------------------------------------------
__global__ __launch_bounds__(512)
void attn_k(const _Float16* __restrict__ P, const _Float16* __restrict__ V1,
            const float* __restrict__ rbf, const float* __restrict__ ru,
            const int* __restrict__ idx,
            const float* __restrict__ We, const float* __restrict__ Wer,
            _Float16* __restrict__ O0, _Float16* __restrict__ O1)
{
    const int t = threadIdx.x;
    const int sub = t >> 7;
    const int hd = t & 127;
    const int h = hd >> 5;
    const int n = blockIdx.x * 4 + sub;
    __shared__ float WeS[16][128], WerS[16][128];
    __shared__ float rbfS[4][16][16];
    __shared__ float ruS[4][16][4];
    __shared__ int   idxS[4][16];
    __shared__ float logitsS[4][4][16];
    __shared__ float attnS[4][4][16];

    #pragma unroll
    for (int i = 0; i < 4; ++i) {
        int ix = t + i * 512;
        WeS[ix >> 7][ix & 127]  = We[ix];
        WerS[ix >> 7][ix & 127] = Wer[ix];
    }
    ((float*)rbfS[sub])[hd]       = rbf[(size_t)n * 256 + hd];
    ((float*)rbfS[sub])[hd + 128] = rbf[(size_t)n * 256 + 128 + hd];
    if (hd < 16) idxS[sub][hd] = idx[n * 16 + hd];
    if (hd < 48) ruS[sub][hd / 3][hd % 3] = ru[n * 48 + hd];
    float q = (float)P[(size_t)n * 512 + hd];
    __syncthreads();

    #pragma unroll 4
    for (int k = 0; k < 16; ++k) {
        int j = idxS[sub][k];
        float kv = (float)P[(size_t)j * 512 + 128 + hd];
        float racc = 0.f;
        #pragma unroll
        for (int r = 0; r < 16; ++r) racc += rbfS[sub][k][r] * WeS[r][hd];
        kv += racc;
        float prod = q * kv;
        prod += __shfl_xor(prod, 1);
        prod += __shfl_xor(prod, 2);
        prod += __shfl_xor(prod, 4);
        prod += __shfl_xor(prod, 8);
        prod += __shfl_xor(prod, 16);
        if ((hd & 31) == 0) logitsS[sub][h][k] = prod * 0.17677669529663687f;
    }
    __syncthreads();

    {
        float mx = -1e30f;
        #pragma unroll
        for (int k = 0; k < 16; ++k) mx = fmaxf(mx, logitsS[sub][h][k]);
        float aw[16]; float s = 0.f;
        #pragma unroll
        for (int k = 0; k < 16; ++k) { aw[k] = expf(logitsS[sub][h][k] - mx); s += aw[k]; }
        float inv = 1.f / s;
        if ((hd & 31) == 0) {
            #pragma unroll
            for (int k = 0; k < 16; ++k) attnS[sub][h][k] = aw[k] * inv;
        }
    }
    __syncthreads();

    float o0 = 0.f, o1x = 0.f, o1y = 0.f, o1z = 0.f;
    #pragma unroll 4
    for (int k = 0; k < 16; ++k) {
        int j = idxS[sub][k];
        float a = attnS[sub][h][k];
        const _Float16* pj = P + (size_t)j * 512;
        float v0 = (float)pj[256 + hd];
        float ge = (float)pj[384 + hd];
        float racc = 0.f;
        #pragma unroll
        for (int r = 0; r < 16; ++r) racc += rbfS[sub][k][r] * WerS[r][hd];
        ge += racc;
        const _Float16* vj = V1 + (size_t)j * 384;
        o0  += a * v0;
        o1x += a * ((float)vj[hd]       + ge * ruS[sub][k][0]);
        o1y += a * ((float)vj[128 + hd] + ge * ruS[sub][k][1]);
        o1z += a * ((float)vj[256 + hd] + ge * ruS[sub][k][2]);
    }
    O0[(size_t)n * 128 + hd] = (_Float16)o0;
    _Float16* o1p = O1 + (size_t)n * 384;
    o1p[hd] = (_Float16)o1x; o1p[128 + hd] = (_Float16)o1y; o1p[256 + hd] = (_Float16)o1z;
}

// ---------------------------------------------------------------------------
__global__ __launch_bounds__(256)
void vecout_k(const float* __restrict__ f1, const float* __restrict__ wv,
              float* __restrict__ out2)
{
    int row = blockIdx.x * 256 + threadIdx.x;
    if (row >= NPTS * 3) return;
    const float4* fr = (const float4*)(f1 + (size_t)row * 64);
    const float4* w4 = (const float4*)wv;
    float s = 0.f;
    #pragma unroll
    for (int c = 0; c < 16; ++c) {
        float4 a = fr[c], b = w4[c];
        s += a.x * b.x + a.y * b.y + a.z * b.z + a.w * b.w;
    }
    out2[row] = s;
}

// ---------------------------------------------------------------------------
extern "C" void kernel_launch(void* const* d_in, const int* in_sizes, int n_in,
                              void* d_out, int out_size, void* d_ws, size_t ws_size,
                              hipStream_t stream)
{
    (void)in_sizes; (void)n_in; (void)out_size; (void)ws_size;
    const float* feats = (const float*)d_in[0];
    const float* coors = (const float*)d_in[1];
    const float* Wemb = (const float*)d_in[3];
    const float* Wq   = (const float*)d_in[4];
    const float* Wk   = (const float*)d_in[5];
    const float* Wv0  = (const float*)d_in[6];
    const float* Wvr  = (const float*)d_in[7];
    const float* We   = (const float*)d_in[8];
    const float* Wer  = (const float*)d_in[9];
    const float* Wv1  = (const float*)d_in[10];
    const float* Wo0  = (const float*)d_in[11];
    const float* Wo1  = (const float*)d_in[12];
    const float* Wf1  = (const float*)d_in[13];
    const float* bf1  = (const float*)d_in[14];
    const float* Wf2  = (const float*)d_in[15];
    const float* bf2  = (const float*)d_in[16];
    const float* Wg   = (const float*)d_in[17];
    const float* Wvff = (const float*)d_in[18];
    const float* Ws   = (const float*)d_in[19];
    const float* bs   = (const float*)d_in[20];
    const float* wv   = (const float*)d_in[21];
    float* out = (float*)d_out;

    char* ws = (char*)d_ws;
    size_t off = 0;
    auto carve = [&](size_t bytes) -> char* {
        char* p = ws + off;
        off += (bytes + 255) & ~(size_t)255;
        return p;
    };
    int*      idxp   = (int*)      carve((size_t)NPTS * 16 * 4);
    float*    rbfp   = (float*)    carve((size_t)NPTS * 256 * 4);
    float*    rup    = (float*)    carve((size_t)NPTS * 48 * 4);
    float*    f0     = (float*)    carve((size_t)NPTS * 256 * 4);
    float*    f1     = (float*)    carve((size_t)NPTS * 192 * 4);
    float*    gt     = (float*)    carve((size_t)NPTS * 64 * 4);
    _Float16* f0n_h  = (_Float16*) carve((size_t)NPTS * 256 * 2);
    _Float16* f0h    = (_Float16*) carve((size_t)NPTS * 256 * 2);
    _Float16* f1h    = (_Float16*) carve((size_t)NPTS * 192 * 2);
    _Float16* O1h    = (_Float16*) carve((size_t)NPTS * 384 * 2);
    _Float16* featsh = (_Float16*) carve((size_t)NPTS * 256 * 2);
    // Ph + V1h + O0h contiguous; Hbh (10000x1024 f16) aliases them.
    _Float16* Ph     = (_Float16*) carve((size_t)NPTS * 512 * 2);
    _Float16* V1h    = (_Float16*) carve((size_t)NPTS * 384 * 2);
    _Float16* O0h    = (_Float16*) carve((size_t)NPTS * 128 * 2);
    _Float16* Hbh    = Ph;
    _Float16* WembT  = (_Float16*) carve(65536 * 2);
    _Float16* WqkvrT = (_Float16*) carve(4 * 131072 * 2);
    _Float16* Wv1T   = (_Float16*) carve(4 * 8192 * 2);
    _Float16* Wo0T   = (_Float16*) carve(4 * 32768 * 2);
    _Float16* Wo1T   = (_Float16*) carve(4 * 8192 * 2);
    _Float16* WfgT   = (_Float16*) carve(4 * 278528 * 2);   // [Wf1(1024) ; Wg(64)] x 256
    _Float16* Wf2T   = (_Float16*) carve(4 * 262144 * 2);
    _Float16* WvffT  = (_Float16*) carve(4 * 4096 * 2);
    _Float16* WsT    = (_Float16*) carve(65536 * 2);

    // ---- weight transpose-convert (46 descriptors, one launch) ----
    TXA ta;
    int blk = 0, di = 0;
    auto addt = [&](const float* s, _Float16* d, int Ks, int Ns) {
        ta.t[di].src = s; ta.t[di].dst = d; ta.t[di].K = Ks; ta.t[di].N = Ns;
        ta.t[di].blk0 = blk; blk += (Ks / 32) * (Ns / 32); ++di;
    };
    addt(Wemb, WembT, 256, 256);
    for (int l = 0; l < 4; ++l) {
        addt(Wq  + l * 32768, WqkvrT + (size_t)l * 131072 +     0, 256, 128);
        addt(Wk  + l * 32768, WqkvrT + (size_t)l * 131072 + 32768, 256, 128);
        addt(Wv0 + l * 32768, WqkvrT + (size_t)l * 131072 + 65536, 256, 128);
        addt(Wvr + l * 32768, WqkvrT + (size_t)l * 131072 + 98304, 256, 128);
    }
    for (int l = 0; l < 4; ++l) addt(Wv1  + l * 8192,   Wv1T  + l * 8192,   64, 128);
    for (int l = 0; l < 4; ++l) addt(Wo0  + l * 32768,  Wo0T  + l * 32768,  128, 256);
    for (int l = 0; l < 4; ++l) addt(Wo1  + l * 8192,   Wo1T  + l * 8192,   128, 64);
    for (int l = 0; l < 4; ++l) {
        addt(Wf1 + l * 262144, WfgT + (size_t)l * 278528,          256, 1024);
        addt(Wg  + l * 16384,  WfgT + (size_t)l * 278528 + 262144, 256, 64);
    }
    for (int l = 0; l < 4; ++l) addt(Wf2  + l * 262144, Wf2T  + l * 262144, 1024, 256);
    for (int l = 0; l < 4; ++l) addt(Wvff + l * 4096,   WvffT + l * 4096,   64, 64);
    addt(Ws, WsT, 256, 256);
    tconv_k<<<blk, 256, 0, stream>>>(ta);

    cvt_k<<<1250, 256, 0, stream>>>(feats, featsh, NPTS * 256 / 8);
    knn_k<<<1250, 512, 0, stream>>>(coors, idxp, rbfp, rup);

    // TAG 0: f0 = feats @ Wemb
    {
        GA ga{}; ga.nd = 1;
        GD& g = ga.g[0];
        g.A = featsh; g.lda = 256; g.Bt = WembT; g.C = f0; g.ldc = 256;
        g.M = NPTS; g.N = 256; g.K = 256; g.mode = MO32; g.blk0 = 0; g.nbx = 4;
        gemm_b<0,false><<<628, 256, 0, stream>>>(ga);
    }
    (void)hipMemsetAsync(f1, 0, (size_t)NPTS * 192 * 4, stream);
    (void)hipMemsetAsync(f1h, 0, (size_t)NPTS * 192 * 2, stream);

    for (int l = 0; l < 4; ++l) {
        ln_k<<<2500, 256, 0, stream>>>(f0, f0n_h, NPTS);
        // TAG 1: Ph = f16(f0n @ Wqkvr)  ||  V1h = f16(f1h @ Wv1)
        {
            GA ga{}; ga.nd = 2;
            GD& p = ga.g[0];
            p.A = f0n_h; p.lda = 256; p.Bt = WqkvrT + (size_t)l * 131072; p.Ch = Ph; p.ldc = 512;
            p.M = NPTS; p.N = 512; p.K = 256; p.mode = MO16; p.blk0 = 0; p.nbx = 8;
            GD& v = ga.g[1];
            v.A = f1h; v.lda = 64; v.Bt = Wv1T + l * 8192; v.Ch = V1h; v.ldc = 128;
            v.M = NPTS * 3; v.N = 128; v.K = 64; v.mode = MO16; v.blk0 = 1256; v.nbx = 2;
            gemm_b<1,false><<<1256 + 938, 256, 0, stream>>>(ga);
        }
        attn_k<<<2500, 512, 0, stream>>>(Ph, V1h, rbfp, rup, idxp, We + l * 2048, Wer + l * 2048, O0h, O1h);
        // TAG 2: f0 += O0 @ Wo0  ||  f1 += O1 @ Wo1 (+ f16 mirror)
        {
            GA ga{}; ga.nd = 2;
            GD& a = ga.g[0];
            a.A = O0h; a.lda = 128; a.Bt = Wo0T + l * 32768; a.C = f0; a.ldc = 256;
            a.M = NPTS; a.N = 256; a.K = 128; a.mode = MADD | MO32; a.blk0 = 0; a.nbx = 4;
            GD& b = ga.g[1];
            b.A = O1h; b.lda = 128; b.Bt = Wo1T + l * 8192; b.C = f1; b.Ch = f1h; b.ldc = 64;
            b.M = NPTS * 3; b.N = 64; b.K = 128; b.mode = MADD | MO32 | MO16; b.blk0 = 628; b.nbx = 1;
            gemm_b<2,false><<<628 + 469, 256, 0, stream>>>(ga);
        }
        ln_k<<<2500, 256, 0, stream>>>(f0, f0n_h, NPTS);
        // TAG 3: Hb = gelu(f0n@Wf1+bf1) f16; gate = sigmoid(f0n@Wg)   (N=1088)
        {
            GA ga{}; ga.nd = 1;
            GD& g = ga.g[0];
            g.A = f0n_h; g.lda = 256; g.Bt = WfgT + (size_t)l * 278528; g.bias = bf1 + l * 1024;
            g.Ch = Hbh; g.ldc = 1024; g.gout = gt;
            g.M = NPTS; g.N = 1088; g.K = 256; g.mode = MSPLIT | MBIAS; g.blk0 = 0; g.nbx = 17;
            gemm_b<3,false><<<17 * 157, 256, 0, stream>>>(ga);
        }
        // TAG 4 (DBUF): f0 += Hb @ Wf2 + bf2  ||  f1 += (f1h @ Wvff)*gate (+mirror)
        {
            GA ga{}; ga.nd = 2;
            GD& a = ga.g[0];
            a.A = Hbh; a.lda = 1024; a.Bt = Wf2T + (size_t)l * 262144; a.bias = bf2 + l * 256;
            a.C = f0; a.ldc = 256;
            a.M = NPTS; a.N = 256; a.K = 1024;
            a.mode = MADD | MBIAS | MO32 | (l == 3 ? MO16 : 0);
            if (l == 3) a.Ch = f0h;
            a.blk0 = 0; a.nbx = 4;
            GD& b = ga.g[1];
            b.A = f1h; b.lda = 64; b.Bt = WvffT + l * 4096; b.gptr = gt;
            b.C = f1; b.Ch = f1h; b.ldc = 64;
            b.M = NPTS * 3; b.N = 64; b.K = 64; b.mode = MADD | MGATED | MO32 | MO16;
            b.blk0 = 628; b.nbx = 1;
            gemm_b<4,true><<<628 + 469, 256, 0, stream>>>(ga);
        }
    }

    // TAG 5: pred_scalar = f0h @ Ws + bs
    {
        GA ga{}; ga.nd = 1;
        GD& g = ga.g[0];
        g.A = f0h; g.lda = 256; g.Bt = WsT; g.bias = bs; g.C = out; g.ldc = 256;
        g.M = NPTS; g.N = 256; g.K = 256; g.mode = MBIAS | MO32; g.blk0 = 0; g.nbx = 4;
        gemm_b<5,false><<<628, 256, 0, stream>>>(ga);
    }
    // pred_vector
    vecout_k<<<118, 256, 0, stream>>>(f1, wv, out + (size_t)NPTS * 256);
}